// Round 13
// baseline (96.835 us; speedup 1.0000x reference)
//
#include <hip/hip_runtime.h>

// ConvCaps EM routing, MI355X — fused kernel + one-time W transpose.
// Geometry: b=16 -> 576 positions; N=288 input caps; C=32; ITERS=3.
//
// Ladder: R1 107us -> R9 85.6us (fused lean f32x2 loop) -> R11/R12 ILP
// attempts both regressed (89/93us, VALUBusy fell). Model revision: the
// per-step pose ds_read_b128 broadcasts are 4KB LOGICAL LDS traffic per n
// (b128 ~85B/cy logical, m134) -> LDS pipe ~2.5x oversubscribed at 9
// waves/CU -> VALUBusy pinned ~47%. Explains R3 (2x waves -> duty FELL to
// 33%) and both ILP failures (pipe-bound, not latency-bound).
// R13: pose read directly from GLOBAL x (same-addr loads dedup to 1-2
// transactions, L1/L2 cached; ~64B/n on VMEM vs 4KB logical on LDS).
// LDS keeps only reduce scratch + consts + 1 ds_swizzle/step.
// R2/R5: launch_bounds cap below demand -> spill. R7: grid.sync hang. Banned.

#define LN2PI 1.8378770664093453f
#define LOG2E 1.4426950408889634f

typedef __attribute__((ext_vector_type(2))) float f32x2;
#define FMA2(a, b, c) __builtin_elementwise_fma((a), (b), (c))
__device__ __forceinline__ f32x2 splat2(float x) { f32x2 r; r.x = x; r.y = x; return r; }

// DPP butterfly add over 32-lane group (never crosses the half-wave boundary).
#define DPP_ADD(x, ctrl) \
    ((x) + __int_as_float(__builtin_amdgcn_update_dpp( \
        0, __float_as_int(x), (ctrl), 0xF, 0xF, true)))

__device__ __forceinline__ float sum32(float e) {
    float s = e;
    s = DPP_ADD(s, 0xB1);   // quad_perm(1,0,3,2): xor1
    s = DPP_ADD(s, 0x4E);   // quad_perm(2,3,0,1): xor2
    s = DPP_ADD(s, 0x141);  // row_half_mirror: xor4
    s = DPP_ADD(s, 0x140);  // row_mirror:      xor8
    s += __shfl_xor(s, 16); // single DS op per step
    return s;
}

// ---------------- W transpose: W[n][c][q] -> Wt[(n*4+q)*32 + c] (float4) ----
__global__ __launch_bounds__(256)
void wtrans(const float4* __restrict__ W4, float4* __restrict__ Wt)
{
    int idx = blockIdx.x * 256 + threadIdx.x;     // 288*32*4 = 36864 float4
    if (idx < 36864) {
        int n = idx >> 7;
        int r = idx & 127;
        int c = r >> 2, q = r & 3;
        Wt[((n * 4 + q) << 5) + c] = W4[idx];
    }
}

// ---------------- fused EM kernel ----------------
// 576 blocks (1/position), 256 thr (4 waves). Each half-wave owns one n per
// step (8 n/step, 36 steps); lane&31 = output capsule c; thread holds 16 il
// as 8 f32x2 pairs. Pose comes straight from global x (dedup'd broadcast).
__global__ __launch_bounds__(256)
void em_fused(const float* __restrict__ x,
              const float* __restrict__ a,
              const float4* __restrict__ Wt,
              const float* __restrict__ bu,
              const float* __restrict__ ba,
              float* __restrict__ out)
{
    __shared__ float ain_s[288];                       //  1152 B
    __shared__ float SA[2][32][17];                    //  4352 B (S1 + R in pad)
    __shared__ float SB[2][32][17];                    //  4352 B (S2)
    __shared__ f32x2 php_s[32][9];                     //  2304 B ({-p*log2e})
    __shared__ f32x2 mh_s[32][9];                      //  2304 B ({2 p mu*log2e})
    __shared__ float A_s[32];                          //   128 B (folded, log2)
    __shared__ float AU_s[32];                         //   128 B (bound, log2)
    // ~14.6 KB

    const int tid  = threadIdx.x;
    const int wv   = tid >> 6;
    const int lane = tid & 63;
    const int half = (lane >> 5) & 1;
    const int c    = lane & 31;

    const int pos = blockIdx.x;          // b*36 + oy*6 + ox
    const int b   = pos / 36;
    const int rem = pos % 36;
    const int oy  = rem / 6, ox = rem % 6;
    const int iy0 = oy * 2, ix0 = ox * 2;

    const float4* x4 = (const float4*)x;

    // ---- stage a patch (pre-scaled by 1/C); pose stays in global ----
    for (int idx = tid; idx < 288; idx += 256) {
        int seg = idx >> 5, bi = idx & 31;
        int kh = seg / 3, kw = seg % 3;
        ain_s[idx] = a[((b * 14 + iy0 + kh) * 14 + (ix0 + kw)) * 32 + bi] * 0.03125f;
    }
    __syncthreads();

    const int n0 = wv * 72 + half;       // first n for this half-wave

    for (int it = 0; it < 3; ++it) {
        f32x2 ph[8], mh[8];
        float Ac = 0.f;
        if (it > 0) {
            #pragma unroll
            for (int j = 0; j < 8; ++j) { ph[j] = php_s[c][j]; mh[j] = mh_s[c][j]; }
            float AU = AU_s[c];
            float m = AU;
            #pragma unroll
            for (int mk = 16; mk >= 1; mk >>= 1)
                m = fmaxf(m, __shfl_xor(m, mk));
            Ac = A_s[c] - m;             // log2 domain; lnap2 - m <= 0 -> exp2 <= 1
        }

        f32x2 s1[8], s2[8];
        #pragma unroll
        for (int j = 0; j < 8; ++j) { s1[j] = splat2(0.f); s2[j] = splat2(0.f); }
        float Racc = 0.f;

        const float4* wp = Wt + (size_t)n0 * 128 + c;
        const float* an  = ain_s + n0;

        // pose pointer for current n (global); recompute at segment wrap
        int n = n0;
        const float4* px;
        {
            int seg = n >> 5, bi = n & 31;
            int kh = (seg * 86) >> 8;            // /3 for seg in 0..8
            int kw = seg - 3 * kh;
            px = x4 + ((size_t)((b * 14 + iy0 + kh) * 14 + (ix0 + kw)) * 32 + bi) * 4;
        }

        for (int s = 0; s < 36; ++s) {
            // W rows (coalesced) + pose rows (dedup'd broadcast from L1/L2)
            float4 wr0 = wp[0], wr1 = wp[32], wr2 = wp[64], wr3 = wp[96];
            float4 pr0 = px[0], pr1 = px[1], pr2 = px[2], pr3 = px[3];

            f32x2 w2[8];
            w2[0].x = wr0.x; w2[0].y = wr0.y;  w2[1].x = wr0.z; w2[1].y = wr0.w;
            w2[2].x = wr1.x; w2[2].y = wr1.y;  w2[3].x = wr1.z; w2[3].y = wr1.w;
            w2[4].x = wr2.x; w2[4].y = wr2.y;  w2[5].x = wr2.z; w2[5].y = wr2.w;
            w2[6].x = wr3.x; w2[6].y = wr3.y;  w2[7].x = wr3.z; w2[7].y = wr3.w;

            f32x2 v2[8];
            #pragma unroll
            for (int i = 0; i < 4; ++i) {
                float4 pr = (i == 0) ? pr0 : (i == 1) ? pr1 : (i == 2) ? pr2 : pr3;
                #pragma unroll
                for (int lp = 0; lp < 2; ++lp) {
                    f32x2 t = splat2(pr.x) * w2[0 + lp];
                    t = FMA2(splat2(pr.y), w2[2 + lp], t);
                    t = FMA2(splat2(pr.z), w2[4 + lp], t);
                    t = FMA2(splat2(pr.w), w2[6 + lp], t);
                    v2[i * 2 + lp] = t;
                }
            }

            float r;
            if (it == 0) {
                r = an[2 * s];
            } else {
                f32x2 acc2 = splat2(0.f);
                acc2.x = Ac;
                #pragma unroll
                for (int j = 0; j < 8; ++j) {
                    f32x2 t = FMA2(ph[j], v2[j], mh[j]);
                    acc2 = FMA2(t, v2[j], acc2);
                }
                float e = __builtin_amdgcn_exp2f(acc2.x + acc2.y);
                float ssum = sum32(e);
                r = __fdividef(e, ssum + 1e-30f);
            }

            Racc += r;
            f32x2 rr = splat2(r);
            #pragma unroll
            for (int j = 0; j < 8; ++j) {
                f32x2 rv = rr * v2[j];
                s1[j] = s1[j] + rv;
                s2[j] = FMA2(rv, v2[j], s2[j]);
            }

            wp += 256;          // 2 n * 4 q * 32 c
            n += 2;
            if ((n & 31) < 2) { // segment wrap: recompute pose base
                int seg = n >> 5, bi = n & 31;
                int kh = (seg * 86) >> 8;
                int kw = seg - 3 * kh;
                px = x4 + ((size_t)((b * 14 + iy0 + kh) * 14 + (ix0 + kw)) * 32 + bi) * 4;
            } else {
                px += 8;        // 2 n * 4 float4
            }
        }

        // combine half-wave partials (same c, disjoint n)
        #pragma unroll
        for (int j = 0; j < 8; ++j) {
            s1[j].x += __shfl_xor(s1[j].x, 32);
            s1[j].y += __shfl_xor(s1[j].y, 32);
            s2[j].x += __shfl_xor(s2[j].x, 32);
            s2[j].y += __shfl_xor(s2[j].y, 32);
        }
        Racc += __shfl_xor(Racc, 32);

        // half-split two-phase reduce: half0 -> SA (S1 + R), half1 -> SB (S2)
        if (wv >= 2) {
            const int row = wv - 2;
            if (half == 0) {
                #pragma unroll
                for (int j = 0; j < 8; ++j) {
                    SA[row][c][2 * j]     = s1[j].x;
                    SA[row][c][2 * j + 1] = s1[j].y;
                }
                SA[row][c][16] = Racc;
            } else {
                #pragma unroll
                for (int j = 0; j < 8; ++j) {
                    SB[row][c][2 * j]     = s2[j].x;
                    SB[row][c][2 * j + 1] = s2[j].y;
                }
            }
        }
        __syncthreads();
        if (wv < 2) {
            if (half == 0) {
                #pragma unroll
                for (int j = 0; j < 8; ++j) {
                    SA[wv][c][2 * j]     += s1[j].x;
                    SA[wv][c][2 * j + 1] += s1[j].y;
                }
                SA[wv][c][16] += Racc;
            } else {
                #pragma unroll
                for (int j = 0; j < 8; ++j) {
                    SB[wv][c][2 * j]     += s2[j].x;
                    SB[wv][c][2 * j + 1] += s2[j].y;
                }
            }
        }
        __syncthreads();

        // ---- in-block finalize: thread = cf*8 + k2 handles il = k2, k2+8 ----
        {
            const int cf = tid >> 3, k2 = tid & 7;
            float R = SA[0][cf][16] + SA[1][cf][16];
            float rinv = __fdividef(1.f, R + 1e-8f);
            float muv[2];
            float tpart = 0.f, Ks = 0.f;
            #pragma unroll
            for (int t2 = 0; t2 < 2; ++t2) {
                int k = k2 + t2 * 8;
                float sv1 = SA[0][cf][k] + SA[1][cf][k];
                float sv2 = SB[0][cf][k] + SB[1][cf][k];
                float mu  = sv1 * rinv;
                float sig = fmaf(-mu, mu, sv2 * rinv);
                sig = fmaxf(sig, 1e-30f);
                float p = __fdividef(0.5f, sig);
                muv[t2] = mu;
                if (it < 2) {
                    ((float*)&php_s[cf][0])[k] = -p * LOG2E;
                    ((float*)&mh_s[cf][0])[k]  = 2.f * p * mu * LOG2E;
                }
                tpart += __logf(sig);
                Ks = fmaf(p * mu, mu, Ks);
            }
            #pragma unroll
            for (int mk = 4; mk >= 1; mk >>= 1) {
                tpart += __shfl_xor(tpart, mk);
                Ks    += __shfl_xor(Ks, mk);
            }
            float cost = R * fmaf(0.5f, tpart, 16.f * bu[cf]);
            float aout = __fdividef(1.f, 1.f + __expf(-(0.001f * (ba[cf] - cost))));

            if (it < 2) {
                if (k2 == 0) {
                    float Afold = __logf(aout) - 0.5f * tpart - 8.0f * LN2PI - Ks;
                    A_s[cf]  = Afold * LOG2E;
                    AU_s[cf] = (Afold + Ks) * LOG2E;
                }
            } else {
                out[(size_t)pos * 512 + cf * 16 + k2]     = muv[0];
                out[(size_t)pos * 512 + cf * 16 + k2 + 8] = muv[1];
                if (k2 == 0)
                    out[294912 + pos * 32 + cf] = aout;
            }
        }
        __syncthreads();
    }
}

// ---------------- legacy single-kernel fallback (R1, known-good 107us) ------
#define NB 288
#define LNSTEP 36
__global__ __launch_bounds__(256, 2)
void convcaps_em_legacy(const float* __restrict__ x, const float* __restrict__ a,
                        const float* __restrict__ W, const float* __restrict__ bu,
                        const float* __restrict__ ba, float* __restrict__ out)
{
    __shared__ __align__(16) float pose_s[NB * 16];
    __shared__ __align__(16) float ain_s[NB];
    __shared__ float S1w[4][32][17];
    __shared__ float S2w[4][32][17];
    __shared__ float Rw[4][32];
    __shared__ float mu_s[32][17];
    __shared__ float p_s[32][17];
    __shared__ float A_s[32];

    const int tid = threadIdx.x, wv = tid >> 6, lane = tid & 63;
    const int half = (lane >> 5) & 1, c = lane & 31;
    const int bid = blockIdx.x, b = bid / 36, rem = bid % 36;
    const int oy = rem / 6, ox = rem % 6, iy0 = oy * 2, ix0 = ox * 2;
    {
        const float4* x4 = (const float4*)x;
        float4* d4 = (float4*)pose_s;
        for (int idx = tid; idx < 1152; idx += 256) {
            int seg = idx >> 7, u = idx & 127, kh = seg / 3, kw = seg % 3;
            d4[idx] = x4[((b * 14 + iy0 + kh) * 14 + (ix0 + kw)) * 128 + u];
        }
        const float4* a4 = (const float4*)a;
        float4* e4 = (float4*)ain_s;
        if (tid < 72) {
            int seg = tid >> 3, u = tid & 7, kh = seg / 3, kw = seg % 3;
            e4[tid] = a4[((b * 14 + iy0 + kh) * 14 + (ix0 + kw)) * 8 + u];
        }
    }
    __syncthreads();
    const float4* W4 = (const float4*)W;
    float muh[16], ph[16], Ac = 0.0f;
    #pragma unroll
    for (int i = 0; i < 16; ++i) { muh[i] = 0.0f; ph[i] = 0.0f; }
    for (int iter = 0; iter < 3; ++iter) {
        if (iter > 0) {
            #pragma unroll
            for (int il = 0; il < 16; ++il) { muh[il] = mu_s[c][il]; ph[il] = p_s[c][il]; }
            Ac = A_s[c];
        }
        float S1[16], S2[16], Racc = 0.0f;
        #pragma unroll
        for (int i = 0; i < 16; ++i) { S1[i] = 0.0f; S2[i] = 0.0f; }
        for (int s = 0; s < LNSTEP; ++s) {
            const int n = wv * 72 + 2 * s + half;
            float wreg[16], preg[16];
            const float4* wp = W4 + (size_t)(n * 32 + c) * 4;
            float4 w0 = wp[0], w1 = wp[1], w2 = wp[2], w3 = wp[3];
            wreg[0]=w0.x; wreg[1]=w0.y; wreg[2]=w0.z; wreg[3]=w0.w;
            wreg[4]=w1.x; wreg[5]=w1.y; wreg[6]=w1.z; wreg[7]=w1.w;
            wreg[8]=w2.x; wreg[9]=w2.y; wreg[10]=w2.z; wreg[11]=w2.w;
            wreg[12]=w3.x; wreg[13]=w3.y; wreg[14]=w3.z; wreg[15]=w3.w;
            const float4* pp = (const float4*)&pose_s[n * 16];
            float4 p0 = pp[0], p1 = pp[1], p2 = pp[2], p3 = pp[3];
            preg[0]=p0.x; preg[1]=p0.y; preg[2]=p0.z; preg[3]=p0.w;
            preg[4]=p1.x; preg[5]=p1.y; preg[6]=p1.z; preg[7]=p1.w;
            preg[8]=p2.x; preg[9]=p2.y; preg[10]=p2.z; preg[11]=p2.w;
            preg[12]=p3.x; preg[13]=p3.y; preg[14]=p3.z; preg[15]=p3.w;
            float v[16];
            #pragma unroll
            for (int i = 0; i < 4; ++i)
                #pragma unroll
                for (int l = 0; l < 4; ++l) {
                    float acc = preg[i*4+0] * wreg[l];
                    acc = fmaf(preg[i*4+1], wreg[4+l], acc);
                    acc = fmaf(preg[i*4+2], wreg[8+l], acc);
                    acc = fmaf(preg[i*4+3], wreg[12+l], acc);
                    v[i*4+l] = acc;
                }
            float r;
            if (iter == 0) r = ain_s[n] * 0.03125f;
            else {
                float acc = 0.0f;
                #pragma unroll
                for (int il = 0; il < 16; ++il) { float d = v[il]-muh[il]; acc = fmaf(-ph[il], d*d, acc); }
                float lnap = Ac + acc, m = lnap;
                #pragma unroll
                for (int mk = 16; mk >= 1; mk >>= 1) m = fmaxf(m, __shfl_xor(m, mk));
                float e = __expf(lnap - m), ssum = e;
                #pragma unroll
                for (int mk = 16; mk >= 1; mk >>= 1) ssum += __shfl_xor(ssum, mk);
                r = __fdividef(e, ssum);
            }
            Racc += r;
            #pragma unroll
            for (int il = 0; il < 16; ++il) { float rv = r * v[il]; S1[il] += rv; S2[il] = fmaf(rv, v[il], S2[il]); }
        }
        #pragma unroll
        for (int il = 0; il < 16; ++il) { S1[il] += __shfl_xor(S1[il], 32); S2[il] += __shfl_xor(S2[il], 32); }
        Racc += __shfl_xor(Racc, 32);
        if (half == 0) {
            #pragma unroll
            for (int il = 0; il < 16; ++il) { S1w[wv][c][il] = S1[il]; S2w[wv][c][il] = S2[il]; }
            Rw[wv][c] = Racc;
        }
        __syncthreads();
        {
            const int c2 = tid >> 3, k = tid & 7;
            float R = Rw[0][c2] + Rw[1][c2] + Rw[2][c2] + Rw[3][c2];
            float rinv = __fdividef(1.0f, R + 1e-8f);
            float muv[2], pv[2], tpart = 0.0f;
            #pragma unroll
            for (int t2 = 0; t2 < 2; ++t2) {
                int il = k + t2 * 8;
                float s1 = S1w[0][c2][il]+S1w[1][c2][il]+S1w[2][c2][il]+S1w[3][c2][il];
                float s2 = S2w[0][c2][il]+S2w[1][c2][il]+S2w[2][c2][il]+S2w[3][c2][il];
                float mu = s1 * rinv;
                float sig = fmaf(-mu, mu, s2 * rinv);
                sig = fmaxf(sig, 1e-30f);
                muv[t2] = mu; pv[t2] = __fdividef(0.5f, sig); tpart += __logf(sig);
            }
            #pragma unroll
            for (int mk = 4; mk >= 1; mk >>= 1) tpart += __shfl_xor(tpart, mk);
            float cost = R * fmaf(0.5f, tpart, 16.0f * bu[c2]);
            float aout = __fdividef(1.0f, 1.0f + __expf(-(0.001f * (ba[c2] - cost))));
            if (iter < 2) {
                #pragma unroll
                for (int t2 = 0; t2 < 2; ++t2) { int il = k + t2*8; mu_s[c2][il] = muv[t2]; p_s[c2][il] = pv[t2]; }
                if (k == 0) A_s[c2] = __logf(aout) - 0.5f * tpart - 8.0f * LN2PI;
            } else {
                #pragma unroll
                for (int t2 = 0; t2 < 2; ++t2) { int il = k + t2*8; out[(size_t)bid*512 + c2*16 + il] = muv[t2]; }
                if (k == 0) out[294912 + bid * 32 + c2] = aout;
            }
        }
        __syncthreads();
    }
}

// ---------------- host ----------------
extern "C" void kernel_launch(void* const* d_in, const int* in_sizes, int n_in,
                              void* d_out, int out_size, void* d_ws, size_t ws_size,
                              hipStream_t stream) {
    (void)in_sizes; (void)n_in; (void)out_size;
    const float* x  = (const float*)d_in[0];
    const float* a  = (const float*)d_in[1];
    const float* w  = (const float*)d_in[2];
    const float* bu = (const float*)d_in[3];
    const float* ba = (const float*)d_in[4];
    float* out = (float*)d_out;
    float* wsf = (float*)d_ws;

    if (ws_size >= (size_t)147456 * 4) {
        float* Wt = wsf;                 // 147456 floats = 576 KB
        hipLaunchKernelGGL(wtrans, dim3(144), dim3(256), 0, stream,
                           (const float4*)w, (float4*)Wt);
        hipLaunchKernelGGL(em_fused, dim3(576), dim3(256), 0, stream,
                           x, a, (const float4*)Wt, bu, ba, out);
    } else {
        hipLaunchKernelGGL(convcaps_em_legacy, dim3(576), dim3(256), 0, stream,
                           x, a, w, bu, ba, out);
    }
}

// Round 14
// 89.702 us; speedup vs baseline: 1.0795x; 1.0795x over previous
//
#include <hip/hip_runtime.h>
#include <hip/hip_fp16.h>

// ConvCaps EM routing, MI355X — fused kernel + one-time W->f16 transpose.
// Geometry: b=16 -> 576 positions; N=288 input caps; C=32; ITERS=3.
//
// Ladder: R1 107 -> R9 85.6us. R11 (prefetch) 89, R12 (2-n ILP) 93, R13
// (pose->global) 97 — all regressed, but VALU-BUSY TIME constant ~41us in
// every variant -> duration = 41us/duty, duty capped ~50%. Diagnosis: L1
// bandwidth on W (4KB per step-wave -> ~594 L1-cy/round vs ~297 VALU-cy at
// 9 waves/CU -> duty 50%). LDS same-addr pose reads broadcast free (R13
// disproved the LDS theory). Fix: W stored f16 -> 2KB per step-wave; v still
// computed in f32 (cvt_f32_f16 x16); quant err ~1e-3 << 0.036 threshold.
// R2/R5: launch_bounds cap below demand -> spill. R7: grid.sync hang. Banned.

#define LN2PI 1.8378770664093453f
#define LOG2E 1.4426950408889634f

typedef __attribute__((ext_vector_type(2))) float f32x2;
#define FMA2(a, b, c) __builtin_elementwise_fma((a), (b), (c))
__device__ __forceinline__ f32x2 splat2(float x) { f32x2 r; r.x = x; r.y = x; return r; }

// DPP butterfly add over 32-lane group (never crosses the half-wave boundary).
#define DPP_ADD(x, ctrl) \
    ((x) + __int_as_float(__builtin_amdgcn_update_dpp( \
        0, __float_as_int(x), (ctrl), 0xF, 0xF, true)))

__device__ __forceinline__ float sum32(float e) {
    float s = e;
    s = DPP_ADD(s, 0xB1);   // quad_perm(1,0,3,2): xor1
    s = DPP_ADD(s, 0x4E);   // quad_perm(2,3,0,1): xor2
    s = DPP_ADD(s, 0x141);  // row_half_mirror: xor4
    s = DPP_ADD(s, 0x140);  // row_mirror:      xor8
    s += __shfl_xor(s, 16);
    return s;
}

__device__ __forceinline__ f32x2 cvt2(unsigned int u) {
    __half2 h = *reinterpret_cast<const __half2*>(&u);
    f32x2 r; r.x = __low2float(h); r.y = __high2float(h);
    return r;
}

// ---- W transpose+quantize: W[n][c][j][l] -> f16 pairs, uint4 rows --------
// Per (n,c): 16 f16 = 2 uint4 rows. Row h of n at Wt16[(n*2+h)*32 + c].
// u32 slot k=2j+lp holds half2{W[j][2lp], W[j][2lp+1]} (matches w2[] order).
__global__ __launch_bounds__(256)
void wtrans16(const float4* __restrict__ W4, uint4* __restrict__ Wt16)
{
    int idx = blockIdx.x * 256 + threadIdx.x;     // 9216 = 288 n * 32 c
    if (idx < 9216) {
        int n = idx >> 5, c = idx & 31;
        const float4* src = W4 + (size_t)(n * 32 + c) * 4;
        float4 w0 = src[0], w1 = src[1], w2 = src[2], w3 = src[3];
        uint4 o0, o1;
        __half2 h;
        h = __floats2half2_rn(w0.x, w0.y); o0.x = *reinterpret_cast<unsigned int*>(&h);
        h = __floats2half2_rn(w0.z, w0.w); o0.y = *reinterpret_cast<unsigned int*>(&h);
        h = __floats2half2_rn(w1.x, w1.y); o0.z = *reinterpret_cast<unsigned int*>(&h);
        h = __floats2half2_rn(w1.z, w1.w); o0.w = *reinterpret_cast<unsigned int*>(&h);
        h = __floats2half2_rn(w2.x, w2.y); o1.x = *reinterpret_cast<unsigned int*>(&h);
        h = __floats2half2_rn(w2.z, w2.w); o1.y = *reinterpret_cast<unsigned int*>(&h);
        h = __floats2half2_rn(w3.x, w3.y); o1.z = *reinterpret_cast<unsigned int*>(&h);
        h = __floats2half2_rn(w3.z, w3.w); o1.w = *reinterpret_cast<unsigned int*>(&h);
        Wt16[(size_t)(n * 2 + 0) * 32 + c] = o0;
        Wt16[(size_t)(n * 2 + 1) * 32 + c] = o1;
    }
}

// ---------------- fused EM kernel ----------------
// 576 blocks (1/position), 256 thr (4 waves). Each half-wave owns one n per
// step (8 n/step, 36 steps); lane&31 = output capsule c; thread holds 16 il
// as 8 f32x2 pairs. W comes as f16 (2 coalesced uint4 loads/step).
__global__ __launch_bounds__(256)
void em_fused(const float* __restrict__ x,
              const float* __restrict__ a,
              const uint4* __restrict__ Wt16,
              const float* __restrict__ bu,
              const float* __restrict__ ba,
              float* __restrict__ out)
{
    __shared__ __align__(16) float4 pose_s[288 * 4];   // 18432 B
    __shared__ float ain_s[288];                       //  1152 B
    __shared__ float SA[2][32][17];                    //  4352 B (S1 + R in pad)
    __shared__ float SB[2][32][17];                    //  4352 B (S2)
    __shared__ f32x2 php_s[32][9];                     //  2304 B ({-p*log2e})
    __shared__ f32x2 mh_s[32][9];                      //  2304 B ({2 p mu*log2e})
    __shared__ float A_s[32];                          //   128 B (folded, log2)
    __shared__ float AU_s[32];                         //   128 B (bound, log2)

    const int tid  = threadIdx.x;
    const int wv   = tid >> 6;
    const int lane = tid & 63;
    const int half = (lane >> 5) & 1;
    const int c    = lane & 31;

    const int pos = blockIdx.x;          // b*36 + oy*6 + ox
    const int b   = pos / 36;
    const int rem = pos % 36;
    const int oy  = rem / 6, ox = rem % 6;
    const int iy0 = oy * 2, ix0 = ox * 2;

    // ---- stage pose patch (1152 float4) + a patch (pre-scaled by 1/C) ----
    {
        const float4* x4 = (const float4*)x;
        for (int idx = tid; idx < 1152; idx += 256) {
            int seg = idx >> 7, u = idx & 127;
            int kh = seg / 3, kw = seg % 3;
            pose_s[idx] = x4[((b * 14 + iy0 + kh) * 14 + (ix0 + kw)) * 128 + u];
        }
        for (int idx = tid; idx < 288; idx += 256) {
            int seg = idx >> 5, bi = idx & 31;
            int kh = seg / 3, kw = seg % 3;
            ain_s[idx] = a[((b * 14 + iy0 + kh) * 14 + (ix0 + kw)) * 32 + bi] * 0.03125f;
        }
    }
    __syncthreads();

    const int n0 = wv * 72 + half;       // first n for this half-wave

    for (int it = 0; it < 3; ++it) {
        f32x2 ph[8], mh[8];
        float Ac = 0.f;
        if (it > 0) {
            #pragma unroll
            for (int j = 0; j < 8; ++j) { ph[j] = php_s[c][j]; mh[j] = mh_s[c][j]; }
            float AU = AU_s[c];
            float m = AU;
            #pragma unroll
            for (int mk = 16; mk >= 1; mk >>= 1)
                m = fmaxf(m, __shfl_xor(m, mk));
            Ac = A_s[c] - m;             // log2 domain; lnap2 - m <= 0 -> exp2 <= 1
        }

        f32x2 s1[8], s2[8];
        #pragma unroll
        for (int j = 0; j < 8; ++j) { s1[j] = splat2(0.f); s2[j] = splat2(0.f); }
        float Racc = 0.f;

        const uint4* wp = Wt16 + (size_t)n0 * 64 + c;   // 64 uint4 per n
        const float4* pp = pose_s + n0 * 4;
        const float* an  = ain_s + n0;

        for (int s = 0; s < 36; ++s) {
            // W rows: 2 coalesced uint4 loads (32B of f16) + pose broadcast
            uint4 ua = wp[0], ub = wp[32];
            float4 pr0 = pp[0], pr1 = pp[1], pr2 = pp[2], pr3 = pp[3];

            f32x2 w2[8];
            w2[0] = cvt2(ua.x); w2[1] = cvt2(ua.y);
            w2[2] = cvt2(ua.z); w2[3] = cvt2(ua.w);
            w2[4] = cvt2(ub.x); w2[5] = cvt2(ub.y);
            w2[6] = cvt2(ub.z); w2[7] = cvt2(ub.w);

            f32x2 v2[8];
            #pragma unroll
            for (int i = 0; i < 4; ++i) {
                float4 pr = (i == 0) ? pr0 : (i == 1) ? pr1 : (i == 2) ? pr2 : pr3;
                #pragma unroll
                for (int lp = 0; lp < 2; ++lp) {
                    f32x2 t = splat2(pr.x) * w2[0 + lp];
                    t = FMA2(splat2(pr.y), w2[2 + lp], t);
                    t = FMA2(splat2(pr.z), w2[4 + lp], t);
                    t = FMA2(splat2(pr.w), w2[6 + lp], t);
                    v2[i * 2 + lp] = t;
                }
            }

            float r;
            if (it == 0) {
                r = an[2 * s];
            } else {
                f32x2 acc2 = splat2(0.f);
                acc2.x = Ac;
                #pragma unroll
                for (int j = 0; j < 8; ++j) {
                    f32x2 t = FMA2(ph[j], v2[j], mh[j]);
                    acc2 = FMA2(t, v2[j], acc2);
                }
                float e = __builtin_amdgcn_exp2f(acc2.x + acc2.y);
                float ssum = sum32(e);
                r = __fdividef(e, ssum + 1e-30f);
            }

            Racc += r;
            f32x2 rr = splat2(r);
            #pragma unroll
            for (int j = 0; j < 8; ++j) {
                f32x2 rv = rr * v2[j];
                s1[j] = s1[j] + rv;
                s2[j] = FMA2(rv, v2[j], s2[j]);
            }

            wp += 128;          // 2 n * 64 uint4
            pp += 8;            // 2 n * 4 float4
        }

        // combine half-wave partials (same c, disjoint n)
        #pragma unroll
        for (int j = 0; j < 8; ++j) {
            s1[j].x += __shfl_xor(s1[j].x, 32);
            s1[j].y += __shfl_xor(s1[j].y, 32);
            s2[j].x += __shfl_xor(s2[j].x, 32);
            s2[j].y += __shfl_xor(s2[j].y, 32);
        }
        Racc += __shfl_xor(Racc, 32);

        // half-split two-phase reduce: half0 -> SA (S1 + R), half1 -> SB (S2)
        if (wv >= 2) {
            const int row = wv - 2;
            if (half == 0) {
                #pragma unroll
                for (int j = 0; j < 8; ++j) {
                    SA[row][c][2 * j]     = s1[j].x;
                    SA[row][c][2 * j + 1] = s1[j].y;
                }
                SA[row][c][16] = Racc;
            } else {
                #pragma unroll
                for (int j = 0; j < 8; ++j) {
                    SB[row][c][2 * j]     = s2[j].x;
                    SB[row][c][2 * j + 1] = s2[j].y;
                }
            }
        }
        __syncthreads();
        if (wv < 2) {
            if (half == 0) {
                #pragma unroll
                for (int j = 0; j < 8; ++j) {
                    SA[wv][c][2 * j]     += s1[j].x;
                    SA[wv][c][2 * j + 1] += s1[j].y;
                }
                SA[wv][c][16] += Racc;
            } else {
                #pragma unroll
                for (int j = 0; j < 8; ++j) {
                    SB[wv][c][2 * j]     += s2[j].x;
                    SB[wv][c][2 * j + 1] += s2[j].y;
                }
            }
        }
        __syncthreads();

        // ---- in-block finalize: thread = cf*8 + k2 handles il = k2, k2+8 ----
        {
            const int cf = tid >> 3, k2 = tid & 7;
            float R = SA[0][cf][16] + SA[1][cf][16];
            float rinv = __fdividef(1.f, R + 1e-8f);
            float muv[2];
            float tpart = 0.f, Ks = 0.f;
            #pragma unroll
            for (int t2 = 0; t2 < 2; ++t2) {
                int k = k2 + t2 * 8;
                float sv1 = SA[0][cf][k] + SA[1][cf][k];
                float sv2 = SB[0][cf][k] + SB[1][cf][k];
                float mu  = sv1 * rinv;
                float sig = fmaf(-mu, mu, sv2 * rinv);
                sig = fmaxf(sig, 1e-30f);
                float p = __fdividef(0.5f, sig);
                muv[t2] = mu;
                if (it < 2) {
                    ((float*)&php_s[cf][0])[k] = -p * LOG2E;
                    ((float*)&mh_s[cf][0])[k]  = 2.f * p * mu * LOG2E;
                }
                tpart += __logf(sig);
                Ks = fmaf(p * mu, mu, Ks);
            }
            #pragma unroll
            for (int mk = 4; mk >= 1; mk >>= 1) {
                tpart += __shfl_xor(tpart, mk);
                Ks    += __shfl_xor(Ks, mk);
            }
            float cost = R * fmaf(0.5f, tpart, 16.f * bu[cf]);
            float aout = __fdividef(1.f, 1.f + __expf(-(0.001f * (ba[cf] - cost))));

            if (it < 2) {
                if (k2 == 0) {
                    float Afold = __logf(aout) - 0.5f * tpart - 8.0f * LN2PI - Ks;
                    A_s[cf]  = Afold * LOG2E;
                    AU_s[cf] = (Afold + Ks) * LOG2E;
                }
            } else {
                out[(size_t)pos * 512 + cf * 16 + k2]     = muv[0];
                out[(size_t)pos * 512 + cf * 16 + k2 + 8] = muv[1];
                if (k2 == 0)
                    out[294912 + pos * 32 + cf] = aout;
            }
        }
        __syncthreads();
    }
}

// ---------------- legacy single-kernel fallback (R1, known-good 107us) ------
#define NB 288
#define LNSTEP 36
__global__ __launch_bounds__(256, 2)
void convcaps_em_legacy(const float* __restrict__ x, const float* __restrict__ a,
                        const float* __restrict__ W, const float* __restrict__ bu,
                        const float* __restrict__ ba, float* __restrict__ out)
{
    __shared__ __align__(16) float pose_s[NB * 16];
    __shared__ __align__(16) float ain_s[NB];
    __shared__ float S1w[4][32][17];
    __shared__ float S2w[4][32][17];
    __shared__ float Rw[4][32];
    __shared__ float mu_s[32][17];
    __shared__ float p_s[32][17];
    __shared__ float A_s[32];

    const int tid = threadIdx.x, wv = tid >> 6, lane = tid & 63;
    const int half = (lane >> 5) & 1, c = lane & 31;
    const int bid = blockIdx.x, b = bid / 36, rem = bid % 36;
    const int oy = rem / 6, ox = rem % 6, iy0 = oy * 2, ix0 = ox * 2;
    {
        const float4* x4 = (const float4*)x;
        float4* d4 = (float4*)pose_s;
        for (int idx = tid; idx < 1152; idx += 256) {
            int seg = idx >> 7, u = idx & 127, kh = seg / 3, kw = seg % 3;
            d4[idx] = x4[((b * 14 + iy0 + kh) * 14 + (ix0 + kw)) * 128 + u];
        }
        const float4* a4 = (const float4*)a;
        float4* e4 = (float4*)ain_s;
        if (tid < 72) {
            int seg = tid >> 3, u = tid & 7, kh = seg / 3, kw = seg % 3;
            e4[tid] = a4[((b * 14 + iy0 + kh) * 14 + (ix0 + kw)) * 8 + u];
        }
    }
    __syncthreads();
    const float4* W4 = (const float4*)W;
    float muh[16], ph[16], Ac = 0.0f;
    #pragma unroll
    for (int i = 0; i < 16; ++i) { muh[i] = 0.0f; ph[i] = 0.0f; }
    for (int iter = 0; iter < 3; ++iter) {
        if (iter > 0) {
            #pragma unroll
            for (int il = 0; il < 16; ++il) { muh[il] = mu_s[c][il]; ph[il] = p_s[c][il]; }
            Ac = A_s[c];
        }
        float S1[16], S2[16], Racc = 0.0f;
        #pragma unroll
        for (int i = 0; i < 16; ++i) { S1[i] = 0.0f; S2[i] = 0.0f; }
        for (int s = 0; s < LNSTEP; ++s) {
            const int n = wv * 72 + 2 * s + half;
            float wreg[16], preg[16];
            const float4* wp = W4 + (size_t)(n * 32 + c) * 4;
            float4 w0 = wp[0], w1 = wp[1], w2 = wp[2], w3 = wp[3];
            wreg[0]=w0.x; wreg[1]=w0.y; wreg[2]=w0.z; wreg[3]=w0.w;
            wreg[4]=w1.x; wreg[5]=w1.y; wreg[6]=w1.z; wreg[7]=w1.w;
            wreg[8]=w2.x; wreg[9]=w2.y; wreg[10]=w2.z; wreg[11]=w2.w;
            wreg[12]=w3.x; wreg[13]=w3.y; wreg[14]=w3.z; wreg[15]=w3.w;
            const float4* pp = (const float4*)&pose_s[n * 16];
            float4 p0 = pp[0], p1 = pp[1], p2 = pp[2], p3 = pp[3];
            preg[0]=p0.x; preg[1]=p0.y; preg[2]=p0.z; preg[3]=p0.w;
            preg[4]=p1.x; preg[5]=p1.y; preg[6]=p1.z; preg[7]=p1.w;
            preg[8]=p2.x; preg[9]=p2.y; preg[10]=p2.z; preg[11]=p2.w;
            preg[12]=p3.x; preg[13]=p3.y; preg[14]=p3.z; preg[15]=p3.w;
            float v[16];
            #pragma unroll
            for (int i = 0; i < 4; ++i)
                #pragma unroll
                for (int l = 0; l < 4; ++l) {
                    float acc = preg[i*4+0] * wreg[l];
                    acc = fmaf(preg[i*4+1], wreg[4+l], acc);
                    acc = fmaf(preg[i*4+2], wreg[8+l], acc);
                    acc = fmaf(preg[i*4+3], wreg[12+l], acc);
                    v[i*4+l] = acc;
                }
            float r;
            if (iter == 0) r = ain_s[n] * 0.03125f;
            else {
                float acc = 0.0f;
                #pragma unroll
                for (int il = 0; il < 16; ++il) { float d = v[il]-muh[il]; acc = fmaf(-ph[il], d*d, acc); }
                float lnap = Ac + acc, m = lnap;
                #pragma unroll
                for (int mk = 16; mk >= 1; mk >>= 1) m = fmaxf(m, __shfl_xor(m, mk));
                float e = __expf(lnap - m), ssum = e;
                #pragma unroll
                for (int mk = 16; mk >= 1; mk >>= 1) ssum += __shfl_xor(ssum, mk);
                r = __fdividef(e, ssum);
            }
            Racc += r;
            #pragma unroll
            for (int il = 0; il < 16; ++il) { float rv = r * v[il]; S1[il] += rv; S2[il] = fmaf(rv, v[il], S2[il]); }
        }
        #pragma unroll
        for (int il = 0; il < 16; ++il) { S1[il] += __shfl_xor(S1[il], 32); S2[il] += __shfl_xor(S2[il], 32); }
        Racc += __shfl_xor(Racc, 32);
        if (half == 0) {
            #pragma unroll
            for (int il = 0; il < 16; ++il) { S1w[wv][c][il] = S1[il]; S2w[wv][c][il] = S2[il]; }
            Rw[wv][c] = Racc;
        }
        __syncthreads();
        {
            const int c2 = tid >> 3, k = tid & 7;
            float R = Rw[0][c2] + Rw[1][c2] + Rw[2][c2] + Rw[3][c2];
            float rinv = __fdividef(1.0f, R + 1e-8f);
            float muv[2], pv[2], tpart = 0.0f;
            #pragma unroll
            for (int t2 = 0; t2 < 2; ++t2) {
                int il = k + t2 * 8;
                float s1 = S1w[0][c2][il]+S1w[1][c2][il]+S1w[2][c2][il]+S1w[3][c2][il];
                float s2 = S2w[0][c2][il]+S2w[1][c2][il]+S2w[2][c2][il]+S2w[3][c2][il];
                float mu = s1 * rinv;
                float sig = fmaf(-mu, mu, s2 * rinv);
                sig = fmaxf(sig, 1e-30f);
                muv[t2] = mu; pv[t2] = __fdividef(0.5f, sig); tpart += __logf(sig);
            }
            #pragma unroll
            for (int mk = 4; mk >= 1; mk >>= 1) tpart += __shfl_xor(tpart, mk);
            float cost = R * fmaf(0.5f, tpart, 16.0f * bu[c2]);
            float aout = __fdividef(1.0f, 1.0f + __expf(-(0.001f * (ba[c2] - cost))));
            if (iter < 2) {
                #pragma unroll
                for (int t2 = 0; t2 < 2; ++t2) { int il = k + t2*8; mu_s[c2][il] = muv[t2]; p_s[c2][il] = pv[t2]; }
                if (k == 0) A_s[c2] = __logf(aout) - 0.5f * tpart - 8.0f * LN2PI;
            } else {
                #pragma unroll
                for (int t2 = 0; t2 < 2; ++t2) { int il = k + t2*8; out[(size_t)bid*512 + c2*16 + il] = muv[t2]; }
                if (k == 0) out[294912 + bid * 32 + c2] = aout;
            }
        }
        __syncthreads();
    }
}

// ---------------- host ----------------
extern "C" void kernel_launch(void* const* d_in, const int* in_sizes, int n_in,
                              void* d_out, int out_size, void* d_ws, size_t ws_size,
                              hipStream_t stream) {
    (void)in_sizes; (void)n_in; (void)out_size;
    const float* x  = (const float*)d_in[0];
    const float* a  = (const float*)d_in[1];
    const float* w  = (const float*)d_in[2];
    const float* bu = (const float*)d_in[3];
    const float* ba = (const float*)d_in[4];
    float* out = (float*)d_out;

    // Wt16 = 288*32*16 f16 = 294912 B
    if (ws_size >= (size_t)294912) {
        uint4* Wt16 = (uint4*)d_ws;
        hipLaunchKernelGGL(wtrans16, dim3(36), dim3(256), 0, stream,
                           (const float4*)w, Wt16);
        hipLaunchKernelGGL(em_fused, dim3(576), dim3(256), 0, stream,
                           x, a, (const uint4*)Wt16, bu, ba, out);
    } else {
        hipLaunchKernelGGL(convcaps_em_legacy, dim3(576), dim3(256), 0, stream,
                           x, a, w, bu, ba, out);
    }
}

// Round 15
// 86.477 us; speedup vs baseline: 1.1198x; 1.0373x over previous
//
#include <hip/hip_runtime.h>

// ConvCaps EM routing, MI355X — fused kernel + one-time W transpose.
// Geometry: b=16 -> 576 positions; N=288 input caps; C=32; ITERS=3.
//
// Ladder: R1 107 -> R9 85.6us (champion). Failed attacks on the 48% duty cap:
// R3/R6 occupancy (convoy/dispatch), R11 prefetch (+VGPR only), R12 2-n ILP,
// R13 pose->global (LDS theory disproved), R14 f16 W (L1-BW theory disproved;
// proved duration = VALU-busy / 0.48: +12% cvt work -> +12% duration).
// R15 = R9 + the only two pure VALU-work reducers: exp2-domain constants
// (kills the ln2 mul in the per-step chain) + 4-way split dist accumulator
// (8-deep FMA chain -> two 4-deep chains + tree). No structural change.
// R2/R5: launch_bounds cap below demand -> spill. R7: grid.sync hang. Banned.

#define LN2PI 1.8378770664093453f
#define LOG2E 1.4426950408889634f

typedef __attribute__((ext_vector_type(2))) float f32x2;
#define FMA2(a, b, c) __builtin_elementwise_fma((a), (b), (c))
__device__ __forceinline__ f32x2 splat2(float x) { f32x2 r; r.x = x; r.y = x; return r; }

// DPP butterfly add over 32-lane group (never crosses the half-wave boundary).
#define DPP_ADD(x, ctrl) \
    ((x) + __int_as_float(__builtin_amdgcn_update_dpp( \
        0, __float_as_int(x), (ctrl), 0xF, 0xF, true)))

__device__ __forceinline__ float sum32(float e) {
    float s = e;
    s = DPP_ADD(s, 0xB1);   // quad_perm(1,0,3,2): xor1
    s = DPP_ADD(s, 0x4E);   // quad_perm(2,3,0,1): xor2
    s = DPP_ADD(s, 0x141);  // row_half_mirror: xor4
    s = DPP_ADD(s, 0x140);  // row_mirror:      xor8
    s += __shfl_xor(s, 16);
    return s;
}

// ---------------- W transpose: W[n][c][q] -> Wt[(n*4+q)*32 + c] (float4) ----
__global__ __launch_bounds__(256)
void wtrans(const float4* __restrict__ W4, float4* __restrict__ Wt)
{
    int idx = blockIdx.x * 256 + threadIdx.x;     // 288*32*4 = 36864 float4
    if (idx < 36864) {
        int n = idx >> 7;
        int r = idx & 127;
        int c = r >> 2, q = r & 3;
        Wt[((n * 4 + q) << 5) + c] = W4[idx];
    }
}

// ---------------- fused EM kernel ----------------
// 576 blocks (1/position), 256 thr (4 waves). Each half-wave owns one n per
// step (8 n/step, 36 steps); lane&31 = output capsule c; thread holds 16 il
// as 8 f32x2 pairs.
__global__ __launch_bounds__(256)
void em_fused(const float* __restrict__ x,
              const float* __restrict__ a,
              const float4* __restrict__ Wt,
              const float* __restrict__ bu,
              const float* __restrict__ ba,
              float* __restrict__ out)
{
    __shared__ __align__(16) float4 pose_s[288 * 4];   // 18432 B
    __shared__ float ain_s[288];                       //  1152 B
    __shared__ float SA[2][32][17];                    //  4352 B (S1 + R in pad)
    __shared__ float SB[2][32][17];                    //  4352 B (S2)
    __shared__ f32x2 php_s[32][9];                     //  2304 B ({-p*log2e})
    __shared__ f32x2 mh_s[32][9];                      //  2304 B ({2 p mu*log2e})
    __shared__ float A_s[32];                          //   128 B (folded, log2)
    __shared__ float AU_s[32];                         //   128 B (bound, log2)

    const int tid  = threadIdx.x;
    const int wv   = tid >> 6;
    const int lane = tid & 63;
    const int half = (lane >> 5) & 1;
    const int c    = lane & 31;

    const int pos = blockIdx.x;          // b*36 + oy*6 + ox
    const int b   = pos / 36;
    const int rem = pos % 36;
    const int oy  = rem / 6, ox = rem % 6;
    const int iy0 = oy * 2, ix0 = ox * 2;

    // ---- stage pose patch (1152 float4) + a patch (pre-scaled by 1/C) ----
    {
        const float4* x4 = (const float4*)x;
        for (int idx = tid; idx < 1152; idx += 256) {
            int seg = idx >> 7, u = idx & 127;
            int kh = seg / 3, kw = seg % 3;
            pose_s[idx] = x4[((b * 14 + iy0 + kh) * 14 + (ix0 + kw)) * 128 + u];
        }
        for (int idx = tid; idx < 288; idx += 256) {
            int seg = idx >> 5, bi = idx & 31;
            int kh = seg / 3, kw = seg % 3;
            ain_s[idx] = a[((b * 14 + iy0 + kh) * 14 + (ix0 + kw)) * 32 + bi] * 0.03125f;
        }
    }
    __syncthreads();

    const int n0 = wv * 72 + half;       // first n for this half-wave

    for (int it = 0; it < 3; ++it) {
        f32x2 ph[8], mh[8];
        float Ac = 0.f;
        if (it > 0) {
            #pragma unroll
            for (int j = 0; j < 8; ++j) { ph[j] = php_s[c][j]; mh[j] = mh_s[c][j]; }
            float AU = AU_s[c];
            float m = AU;
            #pragma unroll
            for (int mk = 16; mk >= 1; mk >>= 1)
                m = fmaxf(m, __shfl_xor(m, mk));
            Ac = A_s[c] - m;             // log2 domain; lnap2 - m <= 0 -> exp2 <= 1
        }

        f32x2 s1[8], s2[8];
        #pragma unroll
        for (int j = 0; j < 8; ++j) { s1[j] = splat2(0.f); s2[j] = splat2(0.f); }
        float Racc = 0.f;

        const float4* wp = Wt + (size_t)n0 * 128 + c;
        const float4* pp = pose_s + n0 * 4;
        const float* an  = ain_s + n0;

        for (int s = 0; s < 36; ++s) {
            // W rows (coalesced) + pose rows (LDS broadcast)
            float4 wr0 = wp[0], wr1 = wp[32], wr2 = wp[64], wr3 = wp[96];
            float4 pr0 = pp[0], pr1 = pp[1], pr2 = pp[2], pr3 = pp[3];

            f32x2 w2[8];
            w2[0].x = wr0.x; w2[0].y = wr0.y;  w2[1].x = wr0.z; w2[1].y = wr0.w;
            w2[2].x = wr1.x; w2[2].y = wr1.y;  w2[3].x = wr1.z; w2[3].y = wr1.w;
            w2[4].x = wr2.x; w2[4].y = wr2.y;  w2[5].x = wr2.z; w2[5].y = wr2.w;
            w2[6].x = wr3.x; w2[6].y = wr3.y;  w2[7].x = wr3.z; w2[7].y = wr3.w;

            f32x2 v2[8];
            #pragma unroll
            for (int i = 0; i < 4; ++i) {
                float4 pr = (i == 0) ? pr0 : (i == 1) ? pr1 : (i == 2) ? pr2 : pr3;
                #pragma unroll
                for (int lp = 0; lp < 2; ++lp) {
                    f32x2 t = splat2(pr.x) * w2[0 + lp];
                    t = FMA2(splat2(pr.y), w2[2 + lp], t);
                    t = FMA2(splat2(pr.z), w2[4 + lp], t);
                    t = FMA2(splat2(pr.w), w2[6 + lp], t);
                    v2[i * 2 + lp] = t;
                }
            }

            float r;
            if (it == 0) {
                r = an[2 * s];
            } else {
                // lnap2 - M = Ac + sum_il [(-p)v + 2pmu]*v  (log2 domain, <= 0)
                // 4-way split: two independent f32x2 chains of 4, tree-combined.
                f32x2 q0 = splat2(0.f), q1 = splat2(0.f);
                #pragma unroll
                for (int j = 0; j < 4; ++j) {
                    f32x2 t0 = FMA2(ph[j],     v2[j],     mh[j]);
                    f32x2 t1 = FMA2(ph[j + 4], v2[j + 4], mh[j + 4]);
                    q0 = FMA2(t0, v2[j],     q0);
                    q1 = FMA2(t1, v2[j + 4], q1);
                }
                float accf = Ac + ((q0.x + q0.y) + (q1.x + q1.y));
                float e = __builtin_amdgcn_exp2f(accf);
                float ssum = sum32(e);
                r = __fdividef(e, ssum + 1e-30f);
            }

            Racc += r;
            f32x2 rr = splat2(r);
            #pragma unroll
            for (int j = 0; j < 8; ++j) {
                f32x2 rv = rr * v2[j];
                s1[j] = s1[j] + rv;
                s2[j] = FMA2(rv, v2[j], s2[j]);
            }

            wp += 256;          // 2 n * 4 q * 32 c
            pp += 8;            // 2 n * 4 float4
        }

        // combine half-wave partials (same c, disjoint n)
        #pragma unroll
        for (int j = 0; j < 8; ++j) {
            s1[j].x += __shfl_xor(s1[j].x, 32);
            s1[j].y += __shfl_xor(s1[j].y, 32);
            s2[j].x += __shfl_xor(s2[j].x, 32);
            s2[j].y += __shfl_xor(s2[j].y, 32);
        }
        Racc += __shfl_xor(Racc, 32);

        // half-split two-phase reduce: half0 -> SA (S1 + R), half1 -> SB (S2)
        if (wv >= 2) {
            const int row = wv - 2;
            if (half == 0) {
                #pragma unroll
                for (int j = 0; j < 8; ++j) {
                    SA[row][c][2 * j]     = s1[j].x;
                    SA[row][c][2 * j + 1] = s1[j].y;
                }
                SA[row][c][16] = Racc;
            } else {
                #pragma unroll
                for (int j = 0; j < 8; ++j) {
                    SB[row][c][2 * j]     = s2[j].x;
                    SB[row][c][2 * j + 1] = s2[j].y;
                }
            }
        }
        __syncthreads();
        if (wv < 2) {
            if (half == 0) {
                #pragma unroll
                for (int j = 0; j < 8; ++j) {
                    SA[wv][c][2 * j]     += s1[j].x;
                    SA[wv][c][2 * j + 1] += s1[j].y;
                }
                SA[wv][c][16] += Racc;
            } else {
                #pragma unroll
                for (int j = 0; j < 8; ++j) {
                    SB[wv][c][2 * j]     += s2[j].x;
                    SB[wv][c][2 * j + 1] += s2[j].y;
                }
            }
        }
        __syncthreads();

        // ---- in-block finalize: thread = cf*8 + k2 handles il = k2, k2+8 ----
        {
            const int cf = tid >> 3, k2 = tid & 7;
            float R = SA[0][cf][16] + SA[1][cf][16];
            float rinv = __fdividef(1.f, R + 1e-8f);
            float muv[2];
            float tpart = 0.f, Ks = 0.f;
            #pragma unroll
            for (int t2 = 0; t2 < 2; ++t2) {
                int k = k2 + t2 * 8;
                float sv1 = SA[0][cf][k] + SA[1][cf][k];
                float sv2 = SB[0][cf][k] + SB[1][cf][k];
                float mu  = sv1 * rinv;
                float sig = fmaf(-mu, mu, sv2 * rinv);
                sig = fmaxf(sig, 1e-30f);
                float p = __fdividef(0.5f, sig);
                muv[t2] = mu;
                if (it < 2) {
                    ((float*)&php_s[cf][0])[k] = -p * LOG2E;
                    ((float*)&mh_s[cf][0])[k]  = 2.f * p * mu * LOG2E;
                }
                tpart += __logf(sig);
                Ks = fmaf(p * mu, mu, Ks);
            }
            #pragma unroll
            for (int mk = 4; mk >= 1; mk >>= 1) {
                tpart += __shfl_xor(tpart, mk);
                Ks    += __shfl_xor(Ks, mk);
            }
            float cost = R * fmaf(0.5f, tpart, 16.f * bu[cf]);
            float aout = __fdividef(1.f, 1.f + __expf(-(0.001f * (ba[cf] - cost))));

            if (it < 2) {
                if (k2 == 0) {
                    float Afold = __logf(aout) - 0.5f * tpart - 8.0f * LN2PI - Ks;
                    A_s[cf]  = Afold * LOG2E;
                    AU_s[cf] = (Afold + Ks) * LOG2E;
                }
            } else {
                out[(size_t)pos * 512 + cf * 16 + k2]     = muv[0];
                out[(size_t)pos * 512 + cf * 16 + k2 + 8] = muv[1];
                if (k2 == 0)
                    out[294912 + pos * 32 + cf] = aout;
            }
        }
        __syncthreads();
    }
}

// ---------------- legacy single-kernel fallback (R1, known-good 107us) ------
#define NB 288
#define LNSTEP 36
__global__ __launch_bounds__(256, 2)
void convcaps_em_legacy(const float* __restrict__ x, const float* __restrict__ a,
                        const float* __restrict__ W, const float* __restrict__ bu,
                        const float* __restrict__ ba, float* __restrict__ out)
{
    __shared__ __align__(16) float pose_s[NB * 16];
    __shared__ __align__(16) float ain_s[NB];
    __shared__ float S1w[4][32][17];
    __shared__ float S2w[4][32][17];
    __shared__ float Rw[4][32];
    __shared__ float mu_s[32][17];
    __shared__ float p_s[32][17];
    __shared__ float A_s[32];

    const int tid = threadIdx.x, wv = tid >> 6, lane = tid & 63;
    const int half = (lane >> 5) & 1, c = lane & 31;
    const int bid = blockIdx.x, b = bid / 36, rem = bid % 36;
    const int oy = rem / 6, ox = rem % 6, iy0 = oy * 2, ix0 = ox * 2;
    {
        const float4* x4 = (const float4*)x;
        float4* d4 = (float4*)pose_s;
        for (int idx = tid; idx < 1152; idx += 256) {
            int seg = idx >> 7, u = idx & 127, kh = seg / 3, kw = seg % 3;
            d4[idx] = x4[((b * 14 + iy0 + kh) * 14 + (ix0 + kw)) * 128 + u];
        }
        const float4* a4 = (const float4*)a;
        float4* e4 = (float4*)ain_s;
        if (tid < 72) {
            int seg = tid >> 3, u = tid & 7, kh = seg / 3, kw = seg % 3;
            e4[tid] = a4[((b * 14 + iy0 + kh) * 14 + (ix0 + kw)) * 8 + u];
        }
    }
    __syncthreads();
    const float4* W4 = (const float4*)W;
    float muh[16], ph[16], Ac = 0.0f;
    #pragma unroll
    for (int i = 0; i < 16; ++i) { muh[i] = 0.0f; ph[i] = 0.0f; }
    for (int iter = 0; iter < 3; ++iter) {
        if (iter > 0) {
            #pragma unroll
            for (int il = 0; il < 16; ++il) { muh[il] = mu_s[c][il]; ph[il] = p_s[c][il]; }
            Ac = A_s[c];
        }
        float S1[16], S2[16], Racc = 0.0f;
        #pragma unroll
        for (int i = 0; i < 16; ++i) { S1[i] = 0.0f; S2[i] = 0.0f; }
        for (int s = 0; s < LNSTEP; ++s) {
            const int n = wv * 72 + 2 * s + half;
            float wreg[16], preg[16];
            const float4* wp = W4 + (size_t)(n * 32 + c) * 4;
            float4 w0 = wp[0], w1 = wp[1], w2 = wp[2], w3 = wp[3];
            wreg[0]=w0.x; wreg[1]=w0.y; wreg[2]=w0.z; wreg[3]=w0.w;
            wreg[4]=w1.x; wreg[5]=w1.y; wreg[6]=w1.z; wreg[7]=w1.w;
            wreg[8]=w2.x; wreg[9]=w2.y; wreg[10]=w2.z; wreg[11]=w2.w;
            wreg[12]=w3.x; wreg[13]=w3.y; wreg[14]=w3.z; wreg[15]=w3.w;
            const float4* pp = (const float4*)&pose_s[n * 16];
            float4 p0 = pp[0], p1 = pp[1], p2 = pp[2], p3 = pp[3];
            preg[0]=p0.x; preg[1]=p0.y; preg[2]=p0.z; preg[3]=p0.w;
            preg[4]=p1.x; preg[5]=p1.y; preg[6]=p1.z; preg[7]=p1.w;
            preg[8]=p2.x; preg[9]=p2.y; preg[10]=p2.z; preg[11]=p2.w;
            preg[12]=p3.x; preg[13]=p3.y; preg[14]=p3.z; preg[15]=p3.w;
            float v[16];
            #pragma unroll
            for (int i = 0; i < 4; ++i)
                #pragma unroll
                for (int l = 0; l < 4; ++l) {
                    float acc = preg[i*4+0] * wreg[l];
                    acc = fmaf(preg[i*4+1], wreg[4+l], acc);
                    acc = fmaf(preg[i*4+2], wreg[8+l], acc);
                    acc = fmaf(preg[i*4+3], wreg[12+l], acc);
                    v[i*4+l] = acc;
                }
            float r;
            if (iter == 0) r = ain_s[n] * 0.03125f;
            else {
                float acc = 0.0f;
                #pragma unroll
                for (int il = 0; il < 16; ++il) { float d = v[il]-muh[il]; acc = fmaf(-ph[il], d*d, acc); }
                float lnap = Ac + acc, m = lnap;
                #pragma unroll
                for (int mk = 16; mk >= 1; mk >>= 1) m = fmaxf(m, __shfl_xor(m, mk));
                float e = __expf(lnap - m), ssum = e;
                #pragma unroll
                for (int mk = 16; mk >= 1; mk >>= 1) ssum += __shfl_xor(ssum, mk);
                r = __fdividef(e, ssum);
            }
            Racc += r;
            #pragma unroll
            for (int il = 0; il < 16; ++il) { float rv = r * v[il]; S1[il] += rv; S2[il] = fmaf(rv, v[il], S2[il]); }
        }
        #pragma unroll
        for (int il = 0; il < 16; ++il) { S1[il] += __shfl_xor(S1[il], 32); S2[il] += __shfl_xor(S2[il], 32); }
        Racc += __shfl_xor(Racc, 32);
        if (half == 0) {
            #pragma unroll
            for (int il = 0; il < 16; ++il) { S1w[wv][c][il] = S1[il]; S2w[wv][c][il] = S2[il]; }
            Rw[wv][c] = Racc;
        }
        __syncthreads();
        {
            const int c2 = tid >> 3, k = tid & 7;
            float R = Rw[0][c2] + Rw[1][c2] + Rw[2][c2] + Rw[3][c2];
            float rinv = __fdividef(1.0f, R + 1e-8f);
            float muv[2], pv[2], tpart = 0.0f;
            #pragma unroll
            for (int t2 = 0; t2 < 2; ++t2) {
                int il = k + t2 * 8;
                float s1 = S1w[0][c2][il]+S1w[1][c2][il]+S1w[2][c2][il]+S1w[3][c2][il];
                float s2 = S2w[0][c2][il]+S2w[1][c2][il]+S2w[2][c2][il]+S2w[3][c2][il];
                float mu = s1 * rinv;
                float sig = fmaf(-mu, mu, s2 * rinv);
                sig = fmaxf(sig, 1e-30f);
                muv[t2] = mu; pv[t2] = __fdividef(0.5f, sig); tpart += __logf(sig);
            }
            #pragma unroll
            for (int mk = 4; mk >= 1; mk >>= 1) tpart += __shfl_xor(tpart, mk);
            float cost = R * fmaf(0.5f, tpart, 16.0f * bu[c2]);
            float aout = __fdividef(1.0f, 1.0f + __expf(-(0.001f * (ba[c2] - cost))));
            if (iter < 2) {
                #pragma unroll
                for (int t2 = 0; t2 < 2; ++t2) { int il = k + t2*8; mu_s[c2][il] = muv[t2]; p_s[c2][il] = pv[t2]; }
                if (k == 0) A_s[c2] = __logf(aout) - 0.5f * tpart - 8.0f * LN2PI;
            } else {
                #pragma unroll
                for (int t2 = 0; t2 < 2; ++t2) { int il = k + t2*8; out[(size_t)bid*512 + c2*16 + il] = muv[t2]; }
                if (k == 0) out[294912 + bid * 32 + c2] = aout;
            }
        }
        __syncthreads();
    }
}

// ---------------- host ----------------
extern "C" void kernel_launch(void* const* d_in, const int* in_sizes, int n_in,
                              void* d_out, int out_size, void* d_ws, size_t ws_size,
                              hipStream_t stream) {
    (void)in_sizes; (void)n_in; (void)out_size;
    const float* x  = (const float*)d_in[0];
    const float* a  = (const float*)d_in[1];
    const float* w  = (const float*)d_in[2];
    const float* bu = (const float*)d_in[3];
    const float* ba = (const float*)d_in[4];
    float* out = (float*)d_out;
    float* wsf = (float*)d_ws;

    if (ws_size >= (size_t)147456 * 4) {
        float* Wt = wsf;                 // 147456 floats = 576 KB
        hipLaunchKernelGGL(wtrans, dim3(144), dim3(256), 0, stream,
                           (const float4*)w, (float4*)Wt);
        hipLaunchKernelGGL(em_fused, dim3(576), dim3(256), 0, stream,
                           x, a, (const float4*)Wt, bu, ba, out);
    } else {
        hipLaunchKernelGGL(convcaps_em_legacy, dim3(576), dim3(256), 0, stream,
                           x, a, w, bu, ba, out);
    }
}